// Round 4
// baseline (578.946 us; speedup 1.0000x reference)
//
#include <hip/hip_runtime.h>
#include <hip/hip_bf16.h>

// Problem constants
#define B 64
#define T 2048
#define D_Q 1024
#define D_V 512
#define ATTN 128
#define FILTERS 32
#define KSIZE 31

// ws layout (floats)
#define PQ_OFF 0                    // [B][ATTN] = 8192
#define CW_OFF 8192                 // [KSIZE][ATTN] = 3968
#define PB_OFF (8192 + 3968)        // [ATTN] = 128
#define SC_OFF (8192 + 3968 + 128)  // [B][T] = 131072 raw scores
#define ML_OFF (SC_OFF + 131072)    // [B][32][2] = 4096 (chunk max, chunk sum)
#define PART_OFF (ML_OFF + 4096)    // [B][32][D_V] = 1048576 partial O
#define CNT_OFF (PART_OFF + 1048576) // [B] int tickets (zeroed by k1)

// d_out layout (floats)
#define AT_OFF 0                 // attention [B][D_V] = 32768
#define AL_OFF 32768             // alignment [B][T] = 131072
#define ST_OFF (32768 + 131072)  // attention_state [B][T] = 131072

typedef float v4f __attribute__((ext_vector_type(4)));

__device__ __forceinline__ float4 nt_load4(const float4* p) {
    v4f v = __builtin_nontemporal_load((const v4f*)p);
    return make_float4(v.x, v.y, v.z, v.w);
}

__device__ __forceinline__ float tanh_fast(float x) {
    float e = __expf(2.f * x);
    return 1.f - 2.f / (e + 1.f);
}

// ---------------------------------------------------------------------------
// K1: blocks 0..63: pq[b][a] = query[b] @ W_q  (parallel GEMV, float4 loads)
//     block 64:     CW[k][a] = ck[k] @ W_loc ; pb[a] = cbias@W_loc + att_bias
//                   + zero the per-b combine tickets (poison-proof)
// ---------------------------------------------------------------------------
__global__ void __launch_bounds__(256)
k1_precompute(const float* __restrict__ query,
              const float* __restrict__ Wq,
              const float* __restrict__ ck,
              const float* __restrict__ cbias,
              const float* __restrict__ Wl,
              const float* __restrict__ abias,
              float* __restrict__ ws) {
    int tid = threadIdx.x;
    if (blockIdx.x < B) {
        int b = blockIdx.x;
        int q = tid & 31;    // a-quad index: a = 4q..4q+3
        int s = tid >> 5;    // d-slice: d in [128s, 128s+128)
        __shared__ __align__(16) float sq[D_Q];
        __shared__ float4 red[256];
        ((float4*)sq)[tid] = ((const float4*)(query + (size_t)b * D_Q))[tid];
        __syncthreads();

        const float4* Wq4 = (const float4*)Wq;  // [D_Q][32]
        float4 acc = make_float4(0.f, 0.f, 0.f, 0.f);
        int dbase = s << 7;
#pragma unroll 16
        for (int i = 0; i < 128; ++i) {
            int d = dbase + i;
            float sd = sq[d];
            float4 w = Wq4[(size_t)d * 32 + q];
            acc.x += sd * w.x; acc.y += sd * w.y;
            acc.z += sd * w.z; acc.w += sd * w.w;
        }
        red[tid] = acc;
        __syncthreads();
        if (tid < 128) {
            float4 o = red[tid + 128];
            acc = red[tid];
            acc.x += o.x; acc.y += o.y; acc.z += o.z; acc.w += o.w;
            red[tid] = acc;
        }
        __syncthreads();
        if (tid < 64) {
            float4 o = red[tid + 64];
            acc = red[tid];
            acc.x += o.x; acc.y += o.y; acc.z += o.z; acc.w += o.w;
            red[tid] = acc;
        }
        __syncthreads();
        if (tid < 32) {
            float4 o = red[tid + 32];
            acc = red[tid];
            acc.x += o.x; acc.y += o.y; acc.z += o.z; acc.w += o.w;
            ((float4*)(ws + PQ_OFF))[b * 32 + tid] = acc;
        }
    } else {
        __shared__ float swl[FILTERS * ATTN];
        for (int i = tid; i < FILTERS * ATTN; i += 256) swl[i] = Wl[i];
        // zero combine tickets (workspace is poisoned every iteration)
        if (tid < B) ((int*)ws)[CNT_OFF + tid] = 0;
        __syncthreads();
        if (tid < ATTN) {
            int a = tid;
            for (int k = 0; k < KSIZE; ++k) {
                float acc = 0.f;
#pragma unroll
                for (int f = 0; f < FILTERS; ++f) acc += ck[k * FILTERS + f] * swl[f * ATTN + a];
                ws[CW_OFF + k * ATTN + a] = acc;
            }
            float pb = abias[a];
#pragma unroll
            for (int f = 0; f < FILTERS; ++f) pb += cbias[f] * swl[f * ATTN + a];
            ws[PB_OFF + a] = pb;
        }
    }
}

// ---------------------------------------------------------------------------
// K2 fused: per 64-t chunk:
//   Phase A: each thread owns 4 consecutive a (float4) x 8 t.
//   Phase B: chunk-local softmax m_c, l_c, weights exp(s-m_c) -> LDS
//   Phase C: partial O_c[d] = sum_t w[t] * values[t][d]
//   Epilogue: device-scope ticket; last block of b performs the full-b
//             combine (M,L over chunks; attention; alignment; state).
// grid = B*32 = 2048 blocks, 256 threads
// ---------------------------------------------------------------------------
__global__ void __launch_bounds__(256)
k2_fused(const float* __restrict__ keys,
         const float* __restrict__ state,
         const float* __restrict__ values,
         const float* __restrict__ vatt,
         float* __restrict__ ws,
         float* __restrict__ out) {
    int bid = blockIdx.x;
    int b = bid >> 5;
    int c = bid & 31;
    int t0 = c << 6;                // 64 t per block
    int tid = threadIdx.x;
    int a4 = tid & 31;              // a = 4*a4 .. 4*a4+3
    int h = tid >> 5;               // t-octet: t_local = 8h .. 8h+7

    __shared__ __align__(16) float sstate[96];
    __shared__ __align__(16) float scw[KSIZE][ATTN];   // 15872 B
    __shared__ float sred[64];      // raw chunk scores
    __shared__ float sal[64];       // exp(s - m_c)
    __shared__ float4 spart[128];

    // state window: sstate[i] = state[b][t0 + i - 15] (0 outside)
    if (tid < 96) {
        int idx = t0 + tid - 15;
        sstate[tid] = (idx >= 0 && idx < T) ? state[b * T + idx] : 0.f;
    }
    // CW -> LDS (3968 floats = 992 float4)
    {
        const float4* cw4 = (const float4*)(ws + CW_OFF);
        float4* dst = (float4*)&scw[0][0];
        for (int i = tid; i < (KSIZE * ATTN) / 4; i += 256) dst[i] = cw4[i];
    }

    // per-thread params (pq + pb folded; v_att)
    float4 pq4, vat4;
    {
        float4 pq = ((const float4*)(ws + PQ_OFF))[b * 32 + a4];
        float4 pb = ((const float4*)(ws + PB_OFF))[a4];
        pq4 = make_float4(pq.x + pb.x, pq.y + pb.y, pq.z + pb.z, pq.w + pb.w);
        vat4 = ((const float4*)vatt)[a4];
    }
    __syncthreads();

    // ---------------- Phase A: scores ----------------
    {
        const float4* sv = (const float4*)sstate;
        float w[40];                 // window sstate[8h .. 8h+39]
        int wq0 = h << 1;
#pragma unroll
        for (int q = 0; q < 10; ++q) {
            float4 v = sv[wq0 + q];
            w[4 * q + 0] = v.x; w[4 * q + 1] = v.y;
            w[4 * q + 2] = v.z; w[4 * q + 3] = v.w;
        }

        // issue all 8 key loads up front; conv covers the latency
        const float4* K4 = (const float4*)keys
                           + ((size_t)b * T + t0 + h * 8) * (ATTN / 4) + a4;
        float4 kv[8];
#pragma unroll
        for (int j = 0; j < 8; ++j)
            kv[j] = nt_load4(&K4[(size_t)j * (ATTN / 4)]);

        float4 acc[8];
#pragma unroll
        for (int j = 0; j < 8; ++j) acc[j] = make_float4(0.f, 0.f, 0.f, 0.f);
#pragma unroll
        for (int k = 0; k < KSIZE; ++k) {
            float4 cwk = ((const float4*)&scw[k][0])[a4];
#pragma unroll
            for (int j = 0; j < 8; ++j) {
                float wv = w[j + k];
                acc[j].x += wv * cwk.x; acc[j].y += wv * cwk.y;
                acc[j].z += wv * cwk.z; acc[j].w += wv * cwk.w;
            }
        }
#pragma unroll
        for (int j = 0; j < 8; ++j) {
            float xx = kv[j].x + pq4.x + acc[j].x;
            float xy = kv[j].y + pq4.y + acc[j].y;
            float xz = kv[j].z + pq4.z + acc[j].z;
            float xw = kv[j].w + pq4.w + acc[j].w;
            float cc = tanh_fast(xx) * vat4.x + tanh_fast(xy) * vat4.y
                     + tanh_fast(xz) * vat4.z + tanh_fast(xw) * vat4.w;
#pragma unroll
            for (int off = 16; off >= 1; off >>= 1) cc += __shfl_xor(cc, off);
            if (a4 == 0) sred[h * 8 + j] = cc;
        }
    }
    __syncthreads();

    // ---------------- Phase B: chunk softmax (wave 0) ----------------
    if (tid < 64) {
        float s = sred[tid];
        ws[SC_OFF + b * T + t0 + tid] = s;      // raw score for combine
        float m = s;
#pragma unroll
        for (int off = 32; off >= 1; off >>= 1) m = fmaxf(m, __shfl_xor(m, off));
        float e = __expf(s - m);
        sal[tid] = e;
        float l = e;
#pragma unroll
        for (int off = 32; off >= 1; off >>= 1) l += __shfl_xor(l, off);
        if (tid == 0) {
            ws[ML_OFF + (b * 32 + c) * 2 + 0] = m;
            ws[ML_OFF + (b * 32 + c) * 2 + 1] = l;
        }
    }
    __syncthreads();

    // ---------------- Phase C: partial attention ----------------
    {
        int d4 = tid & 127;
        int hc = tid >> 7;
        const float4* V = (const float4*)values + ((size_t)b * T + t0) * (D_V / 4) + d4;
        float4 acc = make_float4(0.f, 0.f, 0.f, 0.f);
#pragma unroll 8
        for (int i = 0; i < 32; ++i) {
            int tl = hc * 32 + i;
            float al = sal[tl];
            float4 v = nt_load4(&V[(size_t)tl * (D_V / 4)]);
            acc.x += al * v.x; acc.y += al * v.y;
            acc.z += al * v.z; acc.w += al * v.w;
        }
        if (hc == 1) spart[d4] = acc;
        __syncthreads();
        if (hc == 0) {
            float4 o = spart[d4];
            acc.x += o.x; acc.y += o.y; acc.z += o.z; acc.w += o.w;
            ((float4*)(ws + PART_OFF))[(size_t)(b * 32 + c) * (D_V / 4) + d4] = acc;
        }
    }

    // ---------------- Epilogue: last block of b combines ----------------
    __shared__ int slast;
    __syncthreads();                 // all global writes of this block issued
    if (tid == 0) {
        __threadfence();             // release: partials/SC/ML -> device scope
        int old = atomicAdd(&((int*)ws)[CNT_OFF + b], 1);
        slast = (old == 31);
    }
    __syncthreads();
    if (!slast) return;
    __threadfence();                 // acquire: see other blocks' writes

    __shared__ float sw[32];
    __shared__ float sM, sinvL;
    if (tid < 32) {
        float m = ws[ML_OFF + (b * 32 + tid) * 2 + 0];
        float l = ws[ML_OFF + (b * 32 + tid) * 2 + 1];
        float M = m;
#pragma unroll
        for (int off = 16; off >= 1; off >>= 1) M = fmaxf(M, __shfl_xor(M, off));
        float wgt = __expf(m - M);
        sw[tid] = wgt;
        float L = l * wgt;
#pragma unroll
        for (int off = 16; off >= 1; off >>= 1) L += __shfl_xor(L, off);
        if (tid == 0) { sM = M; sinvL = 1.f / L; }
    }
    __syncthreads();

    float M = sM, invL = sinvL;

    // attention: 512 d over 256 threads (2 each)
#pragma unroll
    for (int r = 0; r < 2; ++r) {
        int d = tid + (r << 8);
        float acc = 0.f;
#pragma unroll 8
        for (int cc = 0; cc < 32; ++cc)
            acc += sw[cc] * ws[PART_OFF + (size_t)(b * 32 + cc) * D_V + d];
        out[AT_OFF + b * D_V + d] = acc * invL;
    }

    // alignment + attention_state: 2048 t over 256 threads (8 each)
#pragma unroll
    for (int k = 0; k < 8; ++k) {
        int t = tid + (k << 8);
        float s = ws[SC_OFF + b * T + t];
        float al = __expf(s - M) * invL;
        out[AL_OFF + b * T + t] = al;
        out[ST_OFF + b * T + t] = al + state[b * T + t];
    }
}

extern "C" void kernel_launch(void* const* d_in, const int* in_sizes, int n_in,
                              void* d_out, int out_size, void* d_ws, size_t ws_size,
                              hipStream_t stream) {
    const float* query  = (const float*)d_in[0];
    const float* values = (const float*)d_in[1];
    const float* keys   = (const float*)d_in[2];
    const float* state  = (const float*)d_in[3];
    const float* Wq     = (const float*)d_in[4];
    const float* ck     = (const float*)d_in[5];
    const float* cbias  = (const float*)d_in[6];
    const float* Wl     = (const float*)d_in[7];
    const float* vatt   = (const float*)d_in[8];
    const float* abias  = (const float*)d_in[9];
    float* out = (float*)d_out;
    float* ws  = (float*)d_ws;

    k1_precompute<<<B + 1, 256, 0, stream>>>(query, Wq, ck, cbias, Wl, abias, ws);
    k2_fused<<<B * (T / 64), 256, 0, stream>>>(keys, state, values, vatt, ws, out);
}

// Round 5
// 417.126 us; speedup vs baseline: 1.3879x; 1.3879x over previous
//
#include <hip/hip_runtime.h>
#include <hip/hip_bf16.h>

// Problem constants
#define B 64
#define T 2048
#define D_Q 1024
#define D_V 512
#define ATTN 128
#define FILTERS 32
#define KSIZE 31

// ws layout (floats)
#define PQ_OFF 0                    // [B][ATTN] = 8192
#define CW_OFF 8192                 // [KSIZE][ATTN] = 3968
#define PB_OFF (8192 + 3968)        // [ATTN] = 128
#define SC_OFF (8192 + 3968 + 128)  // [B][T] = 131072 raw scores
#define ML_OFF (SC_OFF + 131072)    // [B][32][2] = 4096 (chunk max, chunk sum)
#define PART_OFF (ML_OFF + 4096)    // [B][32][D_V] = 1048576 partial O

// d_out layout (floats)
#define AT_OFF 0                 // attention [B][D_V] = 32768
#define AL_OFF 32768             // alignment [B][T] = 131072
#define ST_OFF (32768 + 131072)  // attention_state [B][T] = 131072

typedef float v4f __attribute__((ext_vector_type(4)));

__device__ __forceinline__ float4 nt_load4(const float4* p) {
    v4f v = __builtin_nontemporal_load((const v4f*)p);
    return make_float4(v.x, v.y, v.z, v.w);
}

__device__ __forceinline__ float tanh_fast(float x) {
    float e = __expf(2.f * x);
    return 1.f - 2.f / (e + 1.f);
}

// ---------------------------------------------------------------------------
// K1: blocks 0..63: pq[b][a] = query[b] @ W_q  (parallel GEMV, float4 loads)
//     block 64:     CW[k][a] = ck[k] @ W_loc ; pb[a] = cbias@W_loc + att_bias
// ---------------------------------------------------------------------------
__global__ void __launch_bounds__(256)
k1_precompute(const float* __restrict__ query,
              const float* __restrict__ Wq,
              const float* __restrict__ ck,
              const float* __restrict__ cbias,
              const float* __restrict__ Wl,
              const float* __restrict__ abias,
              float* __restrict__ ws) {
    int tid = threadIdx.x;
    if (blockIdx.x < B) {
        int b = blockIdx.x;
        int q = tid & 31;    // a-quad index: a = 4q..4q+3
        int s = tid >> 5;    // d-slice: d in [128s, 128s+128)
        __shared__ __align__(16) float sq[D_Q];
        __shared__ float4 red[256];
        ((float4*)sq)[tid] = ((const float4*)(query + (size_t)b * D_Q))[tid];
        __syncthreads();

        const float4* Wq4 = (const float4*)Wq;  // [D_Q][32]
        float4 acc = make_float4(0.f, 0.f, 0.f, 0.f);
        int dbase = s << 7;
#pragma unroll 16
        for (int i = 0; i < 128; ++i) {
            int d = dbase + i;
            float sd = sq[d];
            float4 w = Wq4[(size_t)d * 32 + q];
            acc.x += sd * w.x; acc.y += sd * w.y;
            acc.z += sd * w.z; acc.w += sd * w.w;
        }
        red[tid] = acc;
        __syncthreads();
        if (tid < 128) {
            float4 o = red[tid + 128];
            acc = red[tid];
            acc.x += o.x; acc.y += o.y; acc.z += o.z; acc.w += o.w;
            red[tid] = acc;
        }
        __syncthreads();
        if (tid < 64) {
            float4 o = red[tid + 64];
            acc = red[tid];
            acc.x += o.x; acc.y += o.y; acc.z += o.z; acc.w += o.w;
            red[tid] = acc;
        }
        __syncthreads();
        if (tid < 32) {
            float4 o = red[tid + 32];
            acc = red[tid];
            acc.x += o.x; acc.y += o.y; acc.z += o.z; acc.w += o.w;
            ((float4*)(ws + PQ_OFF))[b * 32 + tid] = acc;
        }
    } else {
        __shared__ float swl[FILTERS * ATTN];
        for (int i = tid; i < FILTERS * ATTN; i += 256) swl[i] = Wl[i];
        __syncthreads();
        if (tid < ATTN) {
            int a = tid;
            for (int k = 0; k < KSIZE; ++k) {
                float acc = 0.f;
#pragma unroll
                for (int f = 0; f < FILTERS; ++f) acc += ck[k * FILTERS + f] * swl[f * ATTN + a];
                ws[CW_OFF + k * ATTN + a] = acc;
            }
            float pb = abias[a];
#pragma unroll
            for (int f = 0; f < FILTERS; ++f) pb += cbias[f] * swl[f * ATTN + a];
            ws[PB_OFF + a] = pb;
        }
    }
}

// ---------------------------------------------------------------------------
// K2 fused: per 64-t chunk:
//   Phase A: each thread owns 4 consecutive a (float4) x 8 t.
//     conv via CW in LDS (broadcast reads), keys as float4 nontemporal loads,
//     a-reduce = 3 in-reg adds + 5-level 32-lane butterfly (no LDS combine).
//   Phase B: chunk-local softmax m_c, l_c, weights exp(s-m_c) -> LDS
//   Phase C: partial O_c[d] = sum_t w[t] * values[t][d]  (nontemporal stream)
// grid = B*32 = 2048 blocks, 256 threads
// ---------------------------------------------------------------------------
__global__ void __launch_bounds__(256)
k2_fused(const float* __restrict__ keys,
         const float* __restrict__ state,
         const float* __restrict__ values,
         const float* __restrict__ vatt,
         float* __restrict__ ws) {
    int bid = blockIdx.x;
    int b = bid >> 5;
    int c = bid & 31;
    int t0 = c << 6;                // 64 t per block
    int tid = threadIdx.x;
    int a4 = tid & 31;              // a = 4*a4 .. 4*a4+3
    int h = tid >> 5;               // t-octet: t_local = 8h .. 8h+7

    __shared__ __align__(16) float sstate[96];
    __shared__ __align__(16) float scw[KSIZE][ATTN];   // 15872 B
    __shared__ float sred[64];      // raw chunk scores
    __shared__ float sal[64];       // exp(s - m_c)
    __shared__ float4 spart[128];

    // state window: sstate[i] = state[b][t0 + i - 15] (0 outside)
    if (tid < 96) {
        int idx = t0 + tid - 15;
        sstate[tid] = (idx >= 0 && idx < T) ? state[b * T + idx] : 0.f;
    }
    // CW -> LDS (3968 floats = 992 float4)
    {
        const float4* cw4 = (const float4*)(ws + CW_OFF);
        float4* dst = (float4*)&scw[0][0];
        for (int i = tid; i < (KSIZE * ATTN) / 4; i += 256) dst[i] = cw4[i];
    }

    // per-thread params (pq + pb folded; v_att)
    float4 pq4, vat4;
    {
        float4 pq = ((const float4*)(ws + PQ_OFF))[b * 32 + a4];
        float4 pb = ((const float4*)(ws + PB_OFF))[a4];
        pq4 = make_float4(pq.x + pb.x, pq.y + pb.y, pq.z + pb.z, pq.w + pb.w);
        vat4 = ((const float4*)vatt)[a4];
    }
    __syncthreads();

    // ---------------- Phase A: scores ----------------
    {
        const float4* sv = (const float4*)sstate;
        float w[40];                 // window sstate[8h .. 8h+39]
        int wq0 = h << 1;
#pragma unroll
        for (int q = 0; q < 10; ++q) {
            float4 v = sv[wq0 + q];
            w[4 * q + 0] = v.x; w[4 * q + 1] = v.y;
            w[4 * q + 2] = v.z; w[4 * q + 3] = v.w;
        }

        // issue all 8 key loads up front; conv covers the latency
        const float4* K4 = (const float4*)keys
                           + ((size_t)b * T + t0 + h * 8) * (ATTN / 4) + a4;
        float4 kv[8];
#pragma unroll
        for (int j = 0; j < 8; ++j)
            kv[j] = nt_load4(&K4[(size_t)j * (ATTN / 4)]);

        float4 acc[8];
#pragma unroll
        for (int j = 0; j < 8; ++j) acc[j] = make_float4(0.f, 0.f, 0.f, 0.f);
#pragma unroll
        for (int k = 0; k < KSIZE; ++k) {
            float4 cwk = ((const float4*)&scw[k][0])[a4];
#pragma unroll
            for (int j = 0; j < 8; ++j) {
                float wv = w[j + k];
                acc[j].x += wv * cwk.x; acc[j].y += wv * cwk.y;
                acc[j].z += wv * cwk.z; acc[j].w += wv * cwk.w;
            }
        }
#pragma unroll
        for (int j = 0; j < 8; ++j) {
            float xx = kv[j].x + pq4.x + acc[j].x;
            float xy = kv[j].y + pq4.y + acc[j].y;
            float xz = kv[j].z + pq4.z + acc[j].z;
            float xw = kv[j].w + pq4.w + acc[j].w;
            float cc = tanh_fast(xx) * vat4.x + tanh_fast(xy) * vat4.y
                     + tanh_fast(xz) * vat4.z + tanh_fast(xw) * vat4.w;
#pragma unroll
            for (int off = 16; off >= 1; off >>= 1) cc += __shfl_xor(cc, off);
            if (a4 == 0) sred[h * 8 + j] = cc;
        }
    }
    __syncthreads();

    // ---------------- Phase B: chunk softmax (wave 0) ----------------
    if (tid < 64) {
        float s = sred[tid];
        ws[SC_OFF + b * T + t0 + tid] = s;      // raw score for combine
        float m = s;
#pragma unroll
        for (int off = 32; off >= 1; off >>= 1) m = fmaxf(m, __shfl_xor(m, off));
        float e = __expf(s - m);
        sal[tid] = e;
        float l = e;
#pragma unroll
        for (int off = 32; off >= 1; off >>= 1) l += __shfl_xor(l, off);
        if (tid == 0) {
            ws[ML_OFF + (b * 32 + c) * 2 + 0] = m;
            ws[ML_OFF + (b * 32 + c) * 2 + 1] = l;
        }
    }
    __syncthreads();

    // ---------------- Phase C: partial attention ----------------
    int d4 = tid & 127;
    int hc = tid >> 7;
    const float4* V = (const float4*)values + ((size_t)b * T + t0) * (D_V / 4) + d4;
    float4 acc = make_float4(0.f, 0.f, 0.f, 0.f);
#pragma unroll 8
    for (int i = 0; i < 32; ++i) {
        int tl = hc * 32 + i;
        float al = sal[tl];
        float4 v = nt_load4(&V[(size_t)tl * (D_V / 4)]);
        acc.x += al * v.x; acc.y += al * v.y;
        acc.z += al * v.z; acc.w += al * v.w;
    }
    if (hc == 1) spart[d4] = acc;
    __syncthreads();
    if (hc == 0) {
        float4 o = spart[d4];
        acc.x += o.x; acc.y += o.y; acc.z += o.z; acc.w += o.w;
        ((float4*)(ws + PART_OFF))[(size_t)(b * 32 + c) * (D_V / 4) + d4] = acc;
    }
}

// ---------------------------------------------------------------------------
// K3 combine: 4 blocks per b (all CUs busy). Each block redundantly computes
// M,L over 32 chunks (64 floats), then handles a quarter of d and t.
// grid = 256 blocks, 256 threads
// ---------------------------------------------------------------------------
__global__ void __launch_bounds__(256)
k_combine(const float* __restrict__ state,
          const float* __restrict__ ws,
          float* __restrict__ out) {
    int b = blockIdx.x >> 2;
    int r = blockIdx.x & 3;
    int tid = threadIdx.x;
    __shared__ float sw[32];
    __shared__ float sM, sinvL;

    if (tid < 32) {
        float m = ws[ML_OFF + (b * 32 + tid) * 2 + 0];
        float l = ws[ML_OFF + (b * 32 + tid) * 2 + 1];
        float M = m;
#pragma unroll
        for (int off = 16; off >= 1; off >>= 1) M = fmaxf(M, __shfl_xor(M, off));
        float wgt = __expf(m - M);
        sw[tid] = wgt;
        float L = l * wgt;
#pragma unroll
        for (int off = 16; off >= 1; off >>= 1) L += __shfl_xor(L, off);
        if (tid == 0) { sM = M; sinvL = 1.f / L; }
    }
    __syncthreads();

    float M = sM, invL = sinvL;

    // attention: this block's 128 d
    if (tid < 128) {
        int d = (r << 7) + tid;
        float acc = 0.f;
#pragma unroll 8
        for (int c = 0; c < 32; ++c)
            acc += sw[c] * ws[PART_OFF + (size_t)(b * 32 + c) * D_V + d];
        out[AT_OFF + b * D_V + d] = acc * invL;
    }

    // alignment + attention_state: this block's 512 t
#pragma unroll
    for (int k = 0; k < 2; ++k) {
        int t = (r << 9) + tid + (k << 8);
        float s = ws[SC_OFF + b * T + t];
        float al = __expf(s - M) * invL;
        out[AL_OFF + b * T + t] = al;
        out[ST_OFF + b * T + t] = al + state[b * T + t];
    }
}

extern "C" void kernel_launch(void* const* d_in, const int* in_sizes, int n_in,
                              void* d_out, int out_size, void* d_ws, size_t ws_size,
                              hipStream_t stream) {
    const float* query  = (const float*)d_in[0];
    const float* values = (const float*)d_in[1];
    const float* keys   = (const float*)d_in[2];
    const float* state  = (const float*)d_in[3];
    const float* Wq     = (const float*)d_in[4];
    const float* ck     = (const float*)d_in[5];
    const float* cbias  = (const float*)d_in[6];
    const float* Wl     = (const float*)d_in[7];
    const float* vatt   = (const float*)d_in[8];
    const float* abias  = (const float*)d_in[9];
    float* out = (float*)d_out;
    float* ws  = (float*)d_ws;

    k1_precompute<<<B + 1, 256, 0, stream>>>(query, Wq, ck, cbias, Wl, abias, ws);
    k2_fused<<<B * (T / 64), 256, 0, stream>>>(keys, state, values, vatt, ws);
    k_combine<<<B * 4, 256, 0, stream>>>(state, ws, out);
}